// Round 4
// baseline (280.360 us; speedup 1.0000x reference)
//
#include <hip/hip_runtime.h>

#define NHID   512
#define NCLS   250
#define CHUNK  200
#define NTOK   2048
#define NOUT   (NCLS + CHUNK)    // 450
#define NGRP   4
#define NBLK   (NCLS * NGRP)     // 1000 blocks: (class, row-group)
#define NTHR   256               // 4 waves

// v += lane(v ^ D) within 32-lane swizzle groups
template <int PAT>
__device__ __forceinline__ float swz_add(float v) {
    return v + __int_as_float(__builtin_amdgcn_ds_swizzle(__float_as_int(v), PAT));
}

// Merge two partial-sum regs (tokens A,B) at butterfly distance D with one
// cross-lane op: low lanes keep a-pairs, high lanes keep b-pairs.
template <int D>
__device__ __forceinline__ float comb(float a, float b, int lane) {
    const bool hi = (lane & D) != 0;
    float keep = hi ? b : a;
    float send = hi ? a : b;
    float t = __int_as_float(
        __builtin_amdgcn_ds_swizzle(__float_as_int(send), (D << 10) | 0x1F));
    return keep + t;
}

__global__ __launch_bounds__(NTHR, 3)   // VGPR cap ~170; target 3 waves/EU
void cbd_kernel(const float* __restrict__ x,
                const float* __restrict__ Wc,
                const float* __restrict__ bc,
                const float* __restrict__ Ww,
                const float* __restrict__ bw,
                const int*   __restrict__ cls_idx,
                float* __restrict__ out)
{
    __shared__ int   tok[NTOK];       // 8 KB
    __shared__ float xs[8 * NHID];    // 16 KB: 8 tokens' x rows
    __shared__ int   cnt;

    const int tid = threadIdx.x;
    const int c   = blockIdx.x >> 2;
    const int g   = blockIdx.x & 3;

    // ---- build token list for class c ----
    if (tid == 0) cnt = 0;
    __syncthreads();
    for (int i = tid; i < NTOK; i += NTHR)
        if (cls_idx[i] == c) { int p = atomicAdd(&cnt, 1); tok[p] = i; }
    __syncthreads();
    const int count = cnt;
    if (count == 0) return;

    const int w  = tid >> 6;            // wave 0..3
    const int l  = tid & 63;
    const int rw = 4 * w + g;           // wave's row residue (mod 16)
    const int nr = (NOUT - 1 - rw) / 16 + 1;   // rows r = rw + 16*j, j<nr

    for (int tbase = 0; tbase < count; tbase += 8) {
        const int nt = min(8, count - tbase);

        __syncthreads();  // previous chunk's xs reads done
        // ---- stage 8 token x-rows into LDS (coalesced float4) ----
        for (int idx = tid; idx < 8 * (NHID / 4); idx += NTHR) {
            int row = idx >> 7;            // /128 f4 per row
            int off = (idx & 127) << 2;
            if (row < nt) {
                *(float4*)&xs[row * NHID + off] =
                    *(const float4*)&x[(size_t)tok[tbase + row] * NHID + off];
            } else {
                float4 z = {0.f, 0.f, 0.f, 0.f};
                *(float4*)&xs[row * NHID + off] = z;
            }
        }
        __syncthreads();

        // ---- x slices to registers: lane l owns h in [4l,4l+4) u [256+4l,..) ----
        float4 X0[8], X1[8];
        #pragma unroll
        for (int t = 0; t < 8; ++t) {
            X0[t] = *(const float4*)&xs[t * NHID + 4 * l];
            X1[t] = *(const float4*)&xs[t * NHID + 256 + 4 * l];
        }
        int ti = tbase + (l & 7);
        int mytok = tok[ti < count ? ti : 0];

        auto loadrow = [&](int j, float4& R0, float4& R1) {
            int jj = j < nr ? j : nr - 1;    // clamp overshoot (re-load last row)
            int r  = rw + 16 * jj;
            const float* p = (r < CHUNK) ? (Ww + ((size_t)c * CHUNK + r) * NHID)
                                         : (Wc + (size_t)(r - CHUNK) * NHID);
            R0 = *(const float4*)(p + 4 * l);
            R1 = *(const float4*)(p + 256 + 4 * l);
        };

        auto work = [&](int j, float4 a0, float4 a1) {
            const int r = rw + 16 * j;       // caller guarantees j < nr
            int col; float bias;
            if (r < CHUNK) { col = NCLS + r;  bias = bw[c * CHUNK + r]; }
            else           { col = r - CHUNK; bias = bc[r - CHUNK]; }

            float acc[8];
            #pragma unroll
            for (int t = 0; t < 8; ++t) {
                float4 xa = X0[t], xb = X1[t];
                float s = a0.x * xa.x;
                s = fmaf(a0.y, xa.y, s);
                s = fmaf(a0.z, xa.z, s);
                s = fmaf(a0.w, xa.w, s);
                s = fmaf(a1.x, xb.x, s);
                s = fmaf(a1.y, xb.y, s);
                s = fmaf(a1.z, xb.z, s);
                s = fmaf(a1.w, xb.w, s);
                acc[t] = s;
            }
            float c0 = comb<1>(acc[0], acc[1], l);
            float c1 = comb<1>(acc[2], acc[3], l);
            float c2 = comb<1>(acc[4], acc[5], l);
            float c3 = comb<1>(acc[6], acc[7], l);
            float d0 = comb<2>(c0, c1, l);
            float d1 = comb<2>(c2, c3, l);
            float e  = comb<4>(d0, d1, l);
            e = swz_add<(8  << 10) | 0x1F>(e);
            e = swz_add<(16 << 10) | 0x1F>(e);
            e += __shfl_xor(e, 32, 64);
            if (l < 8 && (tbase + l) < count)
                out[(size_t)mytok * NOUT + col] = e + bias;
        };

        // ---- 6-deep explicit prefetch ring ----
        float4 A0,A1,B0,B1,C0,C1,D0,D1,E0,E1,F0,F1;
        loadrow(0, A0, A1); loadrow(1, B0, B1); loadrow(2, C0, C1);
        loadrow(3, D0, D1); loadrow(4, E0, E1); loadrow(5, F0, F1);
        int j = 0;
        for (; j + 6 <= nr; j += 6) {
            work(j,     A0, A1); loadrow(j + 6,  A0, A1);
            work(j + 1, B0, B1); loadrow(j + 7,  B0, B1);
            work(j + 2, C0, C1); loadrow(j + 8,  C0, C1);
            work(j + 3, D0, D1); loadrow(j + 9,  D0, D1);
            work(j + 4, E0, E1); loadrow(j + 10, E0, E1);
            work(j + 5, F0, F1); loadrow(j + 11, F0, F1);
        }
        if (j     < nr) work(j,     A0, A1);
        if (j + 1 < nr) work(j + 1, B0, B1);
        if (j + 2 < nr) work(j + 2, C0, C1);
        if (j + 3 < nr) work(j + 3, D0, D1);
        if (j + 4 < nr) work(j + 4, E0, E1);
        if (j + 5 < nr) work(j + 5, F0, F1);
    }
}

extern "C" void kernel_launch(void* const* d_in, const int* in_sizes, int n_in,
                              void* d_out, int out_size, void* d_ws, size_t ws_size,
                              hipStream_t stream) {
    const float* x   = (const float*)d_in[0];
    const float* Wc  = (const float*)d_in[1];
    const float* bc  = (const float*)d_in[2];
    const float* Ww  = (const float*)d_in[3];
    const float* bw  = (const float*)d_in[4];
    const int*   cls = (const int*)d_in[5];
    float* out = (float*)d_out;
    hipLaunchKernelGGL(cbd_kernel, dim3(NBLK), dim3(NTHR), 0, stream,
                       x, Wc, bc, Ww, bw, cls, out);
}

// Round 5
// 220.580 us; speedup vs baseline: 1.2710x; 1.2710x over previous
//
#include <hip/hip_runtime.h>

#define NHID   512
#define NCLS   250
#define CHUNK  200
#define NTOK   2048
#define NOUT   (NCLS + CHUNK)    // 450
#define RPH    225               // rows per half
#define NBLK   (NCLS * 2)        // 500 blocks: (class, half)
#define NTHR   256               // 4 waves

// v += lane(v ^ D) within 32-lane swizzle groups
template <int PAT>
__device__ __forceinline__ float swz_add(float v) {
    return v + __int_as_float(__builtin_amdgcn_ds_swizzle(__float_as_int(v), PAT));
}

// Merge two partial-sum regs (tokens A,B) at butterfly distance D with one
// cross-lane op: low lanes keep a-pairs, high lanes keep b-pairs.
template <int D>
__device__ __forceinline__ float comb(float a, float b, int lane) {
    const bool hi = (lane & D) != 0;
    float keep = hi ? b : a;
    float send = hi ? a : b;
    float t = __int_as_float(
        __builtin_amdgcn_ds_swizzle(__float_as_int(send), (D << 10) | 0x1F));
    return keep + t;
}

__global__ __launch_bounds__(NTHR, 2)   // allow up to 256 VGPR: X regs must stay in regs
void cbd_kernel(const float* __restrict__ x,
                const float* __restrict__ Wc,
                const float* __restrict__ bc,
                const float* __restrict__ Ww,
                const float* __restrict__ bw,
                const int*   __restrict__ cls_idx,
                float* __restrict__ out)
{
    __shared__ int   tok[NTOK];        // 8 KB
    __shared__ float bias_s[NOUT];     // 1.8 KB
    __shared__ int   cnt;

    const int tid  = threadIdx.x;
    const int c    = blockIdx.x >> 1;
    const int half = blockIdx.x & 1;

    // ---- token list + bias staging ----
    if (tid == 0) cnt = 0;
    __syncthreads();
    for (int i = tid; i < NTOK; i += NTHR)
        if (cls_idx[i] == c) { int p = atomicAdd(&cnt, 1); tok[p] = i; }
    for (int i = tid; i < NOUT; i += NTHR)
        bias_s[i] = (i < CHUNK) ? bw[c * CHUNK + i] : bc[i - CHUNK];
    __syncthreads();
    const int count = cnt;
    if (count == 0) return;

    const int w = tid >> 6;   // wave 0..3
    const int l = tid & 63;

    // contiguous row span per wave: w0 gets 57 rows, w1-3 get 56
    const int r0 = half * RPH + (w ? 56 * w + 1 : 0);
    const int nr = w ? 56 : 57;

    for (int tbase = 0; tbase < count; tbase += 16) {
        const int nt   = min(16, count - tbase);
        const int noct = (nt + 7) >> 3;

        // ---- x fragments straight from global into registers ----
        // lane l owns h in [4l,4l+4) u [256+4l,256+4l+4)
        float4 X0[2][8], X1[2][8];
        #pragma unroll
        for (int o = 0; o < 2; ++o)
            #pragma unroll
            for (int t = 0; t < 8; ++t) {
                int ti = tbase + o * 8 + t;
                int tk = tok[ti < count ? ti : 0];
                const float* xp = x + (size_t)tk * NHID + 4 * l;
                X0[o][t] = *(const float4*)xp;
                X1[o][t] = *(const float4*)(xp + 256);
            }
        int mytok[2];
        #pragma unroll
        for (int o = 0; o < 2; ++o) {
            int ti = tbase + o * 8 + (l & 7);
            mytok[o] = tok[ti < count ? ti : 0];
        }

        auto loadrow = [&](int j, float4& R0, float4& R1) {
            int jj = j < nr ? j : nr - 1;   // clamp overshoot
            int r  = r0 + jj;
            const float* p = (r < CHUNK) ? (Ww + ((size_t)c * CHUNK + r) * NHID)
                                         : (Wc + (size_t)(r - CHUNK) * NHID);
            R0 = *(const float4*)(p + 4 * l);
            R1 = *(const float4*)(p + 256 + 4 * l);
        };

        auto work = [&](int j, float4 a0, float4 a1) {
            const int r   = r0 + j;          // caller guarantees j < nr
            const int col = (r < CHUNK) ? (NCLS + r) : (r - CHUNK);
            const float bias = bias_s[r];    // LDS, hidden under FMA block

            #pragma unroll
            for (int o = 0; o < 2; ++o) {
                if (o < noct) {
                    float acc[8];
                    #pragma unroll
                    for (int t = 0; t < 8; ++t) {
                        float4 xa = X0[o][t], xb = X1[o][t];
                        float s = a0.x * xa.x;
                        s = fmaf(a0.y, xa.y, s);
                        s = fmaf(a0.z, xa.z, s);
                        s = fmaf(a0.w, xa.w, s);
                        s = fmaf(a1.x, xb.x, s);
                        s = fmaf(a1.y, xb.y, s);
                        s = fmaf(a1.z, xb.z, s);
                        s = fmaf(a1.w, xb.w, s);
                        acc[t] = s;
                    }
                    float c0 = comb<1>(acc[0], acc[1], l);
                    float c1 = comb<1>(acc[2], acc[3], l);
                    float c2 = comb<1>(acc[4], acc[5], l);
                    float c3 = comb<1>(acc[6], acc[7], l);
                    float d0 = comb<2>(c0, c1, l);
                    float d1 = comb<2>(c2, c3, l);
                    float e  = comb<4>(d0, d1, l);
                    e = swz_add<(8  << 10) | 0x1F>(e);
                    e = swz_add<(16 << 10) | 0x1F>(e);
                    e += __shfl_xor(e, 32, 64);
                    if (l < 8 && (tbase + o * 8 + l) < count)
                        out[(size_t)mytok[o] * NOUT + col] = e + bias;
                }
            }
        };

        // ---- 6-deep explicit prefetch ring over contiguous rows ----
        float4 A0,A1,B0,B1,C0,C1,D0,D1,E0,E1,F0,F1;
        loadrow(0, A0, A1); loadrow(1, B0, B1); loadrow(2, C0, C1);
        loadrow(3, D0, D1); loadrow(4, E0, E1); loadrow(5, F0, F1);
        int j = 0;
        for (; j + 6 <= nr; j += 6) {
            work(j,     A0, A1); loadrow(j + 6,  A0, A1);
            work(j + 1, B0, B1); loadrow(j + 7,  B0, B1);
            work(j + 2, C0, C1); loadrow(j + 8,  C0, C1);
            work(j + 3, D0, D1); loadrow(j + 9,  D0, D1);
            work(j + 4, E0, E1); loadrow(j + 10, E0, E1);
            work(j + 5, F0, F1); loadrow(j + 11, F0, F1);
        }
        if (j     < nr) work(j,     A0, A1);
        if (j + 1 < nr) work(j + 1, B0, B1);
        if (j + 2 < nr) work(j + 2, C0, C1);
        if (j + 3 < nr) work(j + 3, D0, D1);
        if (j + 4 < nr) work(j + 4, E0, E1);
        if (j + 5 < nr) work(j + 5, F0, F1);
    }
}

extern "C" void kernel_launch(void* const* d_in, const int* in_sizes, int n_in,
                              void* d_out, int out_size, void* d_ws, size_t ws_size,
                              hipStream_t stream) {
    const float* x   = (const float*)d_in[0];
    const float* Wc  = (const float*)d_in[1];
    const float* bc  = (const float*)d_in[2];
    const float* Ww  = (const float*)d_in[3];
    const float* bw  = (const float*)d_in[4];
    const int*   cls = (const int*)d_in[5];
    float* out = (float*)d_out;
    hipLaunchKernelGGL(cbd_kernel, dim3(NBLK), dim3(NTHR), 0, stream,
                       x, Wc, bc, Ww, bw, cls, out);
}